// Round 9
// baseline (298.020 us; speedup 1.0000x reference)
//
#include <hip/hip_runtime.h>
#include <hip/hip_bf16.h>
#include <hip/hip_fp8.h>

#define NB 8
#define NP 8192
#define IMH 512
#define IMW 512
#define NC 192
#define FH 128
#define FW 128
#define NSTATE 256

#define P1 232   // bf16 K-pitch for X / W1b (K padded to 224); 116 dw, bank-balanced
#define P2 264   // bf16 K-pitch for H1 / W2b (K=256); 132 dw, bank-balanced
#define K1PAD 224
#define CPITCH 72  // conv im2col LDS pitch (bf16): 144 B -> conflict-free b128

typedef __attribute__((ext_vector_type(8))) unsigned short ush8;
typedef __attribute__((ext_vector_type(8))) short short8v;
typedef __attribute__((ext_vector_type(4))) float f32x4;

__device__ __forceinline__ float bf2f(unsigned short u) {
  return __uint_as_float(((unsigned)u) << 16);
}
__device__ __forceinline__ float fp8tof(unsigned char b) {
  __hip_fp8_e4m3 v;
  v.__x = b;
  return (float)v;
}
__device__ __forceinline__ unsigned char ftofp8(float f) {
  __hip_fp8_e4m3 v(f);
  return v.__x;
}

// ---------------- conv as MFMA GEMM: M=pix, N=192, K=48 -> feat fp8 ----
__global__ __launch_bounds__(256) void conv_kernel(
    const float* __restrict__ img, const __hip_bfloat16* __restrict__ wcb,
    const float* __restrict__ bb, unsigned char* __restrict__ feat) {
  __shared__ __hip_bfloat16 Xim[64 * CPITCH];  // 9 KB

  const int tid = threadIdx.x;
  const int lane = tid & 63;
  const int w = tid >> 6;
  const int cl = lane & 15;
  const int kg = lane >> 4;
  const int b = blockIdx.x & 7;
  const int pix0 = (blockIdx.x >> 3) * 64;
  const int y = pix0 >> 7;
  const int xh = (pix0 >> 6) & 1;

  {
    const int pix = tid & 63;
    const int q = tid >> 6;
    *(uint2*)&Xim[pix * CPITCH + 48 + q * 4] = (uint2){0u, 0u};
  }

#pragma unroll
  for (int it = 0; it < 3; ++it) {
    const int idx = it * 256 + tid;  // 0..767
    const int row = idx >> 6;        // ci*4+ky
    const int c = idx & 63;          // local pixel
    const int ci = row >> 2, ky = row & 3;
    const float4 v = *(const float4*)(img + (((size_t)b * 3 + ci) * IMH +
                                             (y * 4 + ky)) * IMW + xh * 256 + c * 4);
    __hip_bfloat16 h[4];
    h[0] = __float2bfloat16(v.x);
    h[1] = __float2bfloat16(v.y);
    h[2] = __float2bfloat16(v.z);
    h[3] = __float2bfloat16(v.w);
    *(uint2*)&Xim[c * CPITCH + ci * 16 + ky * 4] = *(const uint2*)h;
  }
  __syncthreads();

  f32x4 acc[4][3];
#pragma unroll
  for (int mt = 0; mt < 4; ++mt)
#pragma unroll
    for (int nt = 0; nt < 3; ++nt) acc[mt][nt] = (f32x4){0, 0, 0, 0};

#pragma unroll
  for (int kc = 0; kc < 2; ++kc) {
    short8v af[4], bfv[3];
#pragma unroll
    for (int mt = 0; mt < 4; ++mt)
      af[mt] = *(const short8v*)&Xim[(mt * 16 + cl) * CPITCH + kc * 32 + kg * 8];
#pragma unroll
    for (int nt = 0; nt < 3; ++nt)
      bfv[nt] = *(const short8v*)&wcb[(size_t)(w * 48 + nt * 16 + cl) * 64 +
                                      kc * 32 + kg * 8];
#pragma unroll
    for (int mt = 0; mt < 4; ++mt)
#pragma unroll
      for (int nt = 0; nt < 3; ++nt)
        acc[mt][nt] = __builtin_amdgcn_mfma_f32_16x16x32_bf16(
            af[mt], bfv[nt], acc[mt][nt], 0, 0, 0);
  }

#pragma unroll
  for (int nt = 0; nt < 3; ++nt) {
    const float bias = bb[w * 48 + nt * 16 + cl];
#pragma unroll
    for (int mt = 0; mt < 4; ++mt) {
#pragma unroll
      for (int r = 0; r < 4; ++r) {
        feat[((size_t)(w * 8 + b) * 16384 + pix0 + mt * 16 + kg * 4 + r) * 48 +
             nt * 16 + cl] = ftofp8(acc[mt][nt][r] + bias);
      }
    }
  }
}

// ---------------- fused weight prep ----------------
__global__ void prep_all_kernel(
    const float* __restrict__ oW1, const float* __restrict__ cW1,
    const float* __restrict__ oW2, const float* __restrict__ cW2,
    const float* __restrict__ bw, __hip_bfloat16* __restrict__ w1b,
    __hip_bfloat16* __restrict__ w2b, __hip_bfloat16* __restrict__ wcb) {
  const int idx = blockIdx.x * 256 + threadIdx.x;
  const int region = blockIdx.y;
  if (region == 0) {
    if (idx >= 4 * 256 * P1) return;
    const int L = idx / (256 * P1);
    const int rem = idx - L * (256 * P1);
    const int n = rem / P1;
    const int k = rem - n * P1;
    const float* src = (L < 3) ? (oW1 + (size_t)L * 256 * 194) : cW1;
    const int K = (L < 3) ? 194 : 195;
    w1b[idx] = __float2bfloat16((k < K) ? src[(size_t)n * K + k] : 0.0f);
  } else if (region == 1) {
    if (idx >= 4 * 256 * P2) return;
    const int L = idx / (256 * P2);
    const int rem = idx - L * (256 * P2);
    const int n = rem / P2;
    const int k = rem - n * P2;
    const float* src = (L < 3) ? (oW2 + (size_t)L * 65536) : cW2;
    w2b[idx] = __float2bfloat16((k < 256) ? src[(size_t)n * 256 + k] : 0.0f);
  } else {
    if (idx >= 192 * 64) return;
    const int n = idx >> 6;
    const int k = idx & 63;
    wcb[idx] = __float2bfloat16((k < 48) ? bw[(size_t)n * 48 + k] : 0.0f);
  }
}

// ---------------- per-batch masked min of points ----------------
__global__ void mins_kernel(const float* __restrict__ py,
                            const float* __restrict__ mask,
                            float* __restrict__ mins) {
  int b = blockIdx.x;
  float mx = 1e9f, my = 1e9f;
  for (int n = threadIdx.x; n < NP; n += 256) {
    float m = mask[(size_t)b * NP + n];
    float2 p = *(const float2*)&py[((size_t)b * NP + n) * 2];
    mx = fminf(mx, m > 0.0f ? p.x : 1e9f);
    my = fminf(my, m > 0.0f ? p.y : 1e9f);
  }
#pragma unroll
  for (int o = 32; o > 0; o >>= 1) {
    mx = fminf(mx, __shfl_down(mx, o));
    my = fminf(my, __shfl_down(my, o));
  }
  __shared__ float sx[4], sy[4];
  if ((threadIdx.x & 63) == 0) { sx[threadIdx.x >> 6] = mx; sy[threadIdx.x >> 6] = my; }
  __syncthreads();
  if (threadIdx.x == 0) {
    mx = fminf(fminf(sx[0], sx[1]), fminf(sx[2], sx[3]));
    my = fminf(fminf(sy[0], sy[1]), fminf(sy[2], sy[3]));
    mins[b * 2 + 0] = mx;
    mins[b * 2 + 1] = my;
  }
}

// ---------------- standalone gather: barrier-free, max load parallelism ----
// thread = (point m = tid>>2, 48-ch slab j = tid&3); 64 points/block.
// Writes X rows bf16 [b*NP+n][P1] to Xg (cols 0..224; 224..232 unused).
template <bool CLS>
__global__ __launch_bounds__(256) void gather_kernel(
    const unsigned char* __restrict__ feat, const float* __restrict__ p_in,
    const float* __restrict__ mask, const float* __restrict__ mins,
    __hip_bfloat16* __restrict__ Xg) {
  const int tid = threadIdx.x;
  const int m = tid >> 2;
  const int j = tid & 3;
  const int b = blockIdx.x & 7;            // XCD-aligned batch
  const int m0 = (blockIdx.x >> 3) * 64;
  const int n = m0 + m;
  const size_t pidx = (size_t)b * NP + n;
  const float msk = mask[pidx];
  const float2 pv = *(const float2*)&p_in[pidx * 2];
  const float px = pv.x, pyv = pv.y;
  const float xs = px * (127.0f / 128.0f);
  const float ys = pyv * (127.0f / 128.0f);
  const float x0f = floorf(xs), y0f = floorf(ys);
  const float fx = xs - x0f, fy = ys - y0f;
  const int x0 = (int)fminf(fmaxf(x0f, 0.0f), 127.0f);
  const int x1 = (int)fminf(fmaxf(x0f + 1.0f, 0.0f), 127.0f);
  const int y0 = (int)fminf(fmaxf(y0f, 0.0f), 127.0f);
  const int y1 = (int)fminf(fmaxf(y0f + 1.0f, 0.0f), 127.0f);
  const float w00 = (1.0f - fy) * (1.0f - fx);
  const float w01 = (1.0f - fy) * fx;
  const float w10 = fy * (1.0f - fx);
  const float w11 = fy * fx;
  const unsigned char* fb = feat + (size_t)(j * 8 + b) * 16384 * 48;
  const uint4* r00 = (const uint4*)(fb + (size_t)(y0 * FW + x0) * 48);
  const uint4* r01 = (const uint4*)(fb + (size_t)(y0 * FW + x1) * 48);
  const uint4* r10 = (const uint4*)(fb + (size_t)(y1 * FW + x0) * 48);
  const uint4* r11 = (const uint4*)(fb + (size_t)(y1 * FW + x1) * 48);
  __hip_bfloat16* xrow = Xg + pidx * P1;
#pragma unroll
  for (int v = 0; v < 3; ++v) {
    union { uint4 u; unsigned char c[16]; } a0, a1, a2, a3;
    a0.u = r00[v]; a1.u = r01[v]; a2.u = r10[v]; a3.u = r11[v];
    __hip_bfloat16 h[16];
#pragma unroll
    for (int e = 0; e < 16; ++e) {
      float gg = w00 * fp8tof(a0.c[e]) + w01 * fp8tof(a1.c[e]) +
                 w10 * fp8tof(a2.c[e]) + w11 * fp8tof(a3.c[e]);
      h[e] = __float2bfloat16(gg * msk);
    }
    *(ush8*)&xrow[j * 48 + v * 16 + 0] = *(const ush8*)&h[0];
    *(ush8*)&xrow[j * 48 + v * 16 + 8] = *(const ush8*)&h[8];
  }
  if (j == 0) {
    __hip_bfloat16 ex[32];
#pragma unroll
    for (int i = 0; i < 32; ++i) ex[i] = __float2bfloat16(0.0f);
    if constexpr (!CLS) {
      ex[0] = __float2bfloat16((px - mins[b * 2 + 0]) * msk);
      ex[1] = __float2bfloat16((pyv - mins[b * 2 + 1]) * msk);
    } else {
      ex[0] = __float2bfloat16(px);
      ex[1] = __float2bfloat16(pyv);
      const int npv = (n + NP - 1) & (NP - 1);
      const int nnx = (n + 1) & (NP - 1);
      const float2 pp = *(const float2*)&p_in[((size_t)b * NP + npv) * 2];
      const float2 pn = *(const float2*)&p_in[((size_t)b * NP + nnx) * 2];
      const float v1x = pp.x - px, v1y = pp.y - pyv;
      const float v2x = pn.x - px, v2y = pn.y - pyv;
      const float dot = v1x * v2x + v1y * v2y;
      const float nrm =
          sqrtf(v1x * v1x + v1y * v1y) * sqrtf(v2x * v2x + v2y * v2y);
      const float ca = fminf(fmaxf(dot / (nrm + 1e-8f), -1.0f), 1.0f);
      ex[2] = __float2bfloat16(acosf(ca) * msk);
    }
#pragma unroll
    for (int q = 0; q < 4; ++q)
      *(ush8*)&xrow[192 + q * 8] = *(const ush8*)&ex[q * 8];
  }
}

// ---------------- MFMA MLP: coalesced X copy + 3 GEMMs ----------------
// block: 64 points x N=256; 4 waves, wave w owns n in [w*64, w*64+64)
template <bool CLS>
__global__ __launch_bounds__(256, 4) void mlp_kernel(
    const __hip_bfloat16* __restrict__ Xg,
    const float* __restrict__ p_in,
    const float* __restrict__ mask,
    const __hip_bfloat16* __restrict__ W1b, const float* __restrict__ b1,
    const __hip_bfloat16* __restrict__ W2b, const float* __restrict__ b2,
    const float* __restrict__ W3, const float* __restrict__ b3,
    float* __restrict__ out0) {
  __shared__ __hip_bfloat16 Xls[64 * P2];  // X[64][P1] then H1[64][P2]
  __shared__ float red[4][64][2];

  const int tid = threadIdx.x;
  const int lane = tid & 63;
  const int w = tid >> 6;
  const int cl = lane & 15;
  const int kg = lane >> 4;
  const int b = blockIdx.x & 7;             // XCD-aligned batch
  const int m0 = (blockIdx.x >> 3) * 64;

  // ---- coalesced X copy: 64 rows x P1 bf16 = 1856 ush8 ----
  {
    const ush8* src = (const ush8*)(Xg + ((size_t)b * NP + m0) * P1);
    ush8* dst = (ush8*)Xls;
#pragma unroll
    for (int it = 0; it < 8; ++it) {
      const int idx = it * 256 + tid;
      if (idx < 64 * P1 / 8) dst[idx] = src[idx];
    }
  }
  __syncthreads();

  // ---- GEMM1: H1 = relu(X @ W1^T + b1), MFMA bf16 ----
  f32x4 acc[4][4];
#pragma unroll
  for (int mt = 0; mt < 4; ++mt)
#pragma unroll
    for (int nt = 0; nt < 4; ++nt) acc[mt][nt] = (f32x4){0, 0, 0, 0};

  for (int kc = 0; kc < K1PAD / 32; ++kc) {
    short8v af[4], bfv[4];
#pragma unroll
    for (int mt = 0; mt < 4; ++mt)
      af[mt] = *(const short8v*)&Xls[(mt * 16 + cl) * P1 + kc * 32 + kg * 8];
#pragma unroll
    for (int nt = 0; nt < 4; ++nt)
      bfv[nt] = *(const short8v*)&W1b[(size_t)(w * 64 + nt * 16 + cl) * P1 +
                                      kc * 32 + kg * 8];
#pragma unroll
    for (int mt = 0; mt < 4; ++mt)
#pragma unroll
      for (int nt = 0; nt < 4; ++nt)
        acc[mt][nt] = __builtin_amdgcn_mfma_f32_16x16x32_bf16(
            af[mt], bfv[nt], acc[mt][nt], 0, 0, 0);
  }
  __syncthreads();

  // H1 (bias+relu, bf16) -> Xls as [m][P2]
#pragma unroll
  for (int nt = 0; nt < 4; ++nt) {
    const int n = w * 64 + nt * 16 + cl;
    const float bias = b1[n];
#pragma unroll
    for (int mt = 0; mt < 4; ++mt) {
#pragma unroll
      for (int r = 0; r < 4; ++r) {
        const float v = fmaxf(acc[mt][nt][r] + bias, 0.0f);
        Xls[(mt * 16 + kg * 4 + r) * P2 + n] = __float2bfloat16(v);
      }
    }
  }
  __syncthreads();

  // ---- GEMM2 ----
  f32x4 acc2[4][4];
#pragma unroll
  for (int mt = 0; mt < 4; ++mt)
#pragma unroll
    for (int nt = 0; nt < 4; ++nt) acc2[mt][nt] = (f32x4){0, 0, 0, 0};

  for (int kc = 0; kc < 8; ++kc) {
    short8v af[4], bfv[4];
#pragma unroll
    for (int mt = 0; mt < 4; ++mt)
      af[mt] = *(const short8v*)&Xls[(mt * 16 + cl) * P2 + kc * 32 + kg * 8];
#pragma unroll
    for (int nt = 0; nt < 4; ++nt)
      bfv[nt] = *(const short8v*)&W2b[(size_t)(w * 64 + nt * 16 + cl) * P2 +
                                      kc * 32 + kg * 8];
#pragma unroll
    for (int mt = 0; mt < 4; ++mt)
#pragma unroll
      for (int nt = 0; nt < 4; ++nt)
        acc2[mt][nt] = __builtin_amdgcn_mfma_f32_16x16x32_bf16(
            af[mt], bfv[nt], acc2[mt][nt], 0, 0, 0);
  }

  // ---- GEMM3 (f32) + reduction + epilogue ----
  float pr[4][4][2];
#pragma unroll
  for (int mt = 0; mt < 4; ++mt)
#pragma unroll
    for (int r = 0; r < 4; ++r) { pr[mt][r][0] = 0.0f; pr[mt][r][1] = 0.0f; }

#pragma unroll
  for (int nt = 0; nt < 4; ++nt) {
    const int n = w * 64 + nt * 16 + cl;
    const float bias = b2[n];
    const float w3a = W3[n];
    float w3b = 0.0f;
    if constexpr (!CLS) w3b = W3[256 + n];
#pragma unroll
    for (int mt = 0; mt < 4; ++mt) {
#pragma unroll
      for (int r = 0; r < 4; ++r) {
        const float t = fmaxf(acc2[mt][nt][r] + bias, 0.0f);
        pr[mt][r][0] = fmaf(t, w3a, pr[mt][r][0]);
        if constexpr (!CLS) pr[mt][r][1] = fmaf(t, w3b, pr[mt][r][1]);
      }
    }
  }
#pragma unroll
  for (int s = 1; s < 16; s <<= 1) {
#pragma unroll
    for (int mt = 0; mt < 4; ++mt)
#pragma unroll
      for (int r = 0; r < 4; ++r) {
        pr[mt][r][0] += __shfl_xor(pr[mt][r][0], s);
        if constexpr (!CLS) pr[mt][r][1] += __shfl_xor(pr[mt][r][1], s);
      }
  }
  if constexpr (!CLS) {
    if (cl < 8) {
      const int r = cl >> 1, o = cl & 1;
#pragma unroll
      for (int mt = 0; mt < 4; ++mt)
        red[w][mt * 16 + kg * 4 + r][o] = pr[mt][r][o];
    }
  } else {
    if (cl < 4) {
      const int r = cl;
#pragma unroll
      for (int mt = 0; mt < 4; ++mt)
        red[w][mt * 16 + kg * 4 + r][0] = pr[mt][r][0];
    }
  }
  __syncthreads();

  if constexpr (!CLS) {
    if (tid < 128) {
      const int m = tid >> 1, o = tid & 1;
      const float s = red[0][m][o] + red[1][m][o] + red[2][m][o] + red[3][m][o];
      const size_t pidx = (size_t)b * NP + m0 + m;
      const float msk = mask[pidx];
      const float off = (s + b3[o]) * msk;
      out0[pidx * 2 + o] = p_in[pidx * 2 + o] + off * 4.0f;
    }
  } else {
    if (tid < 64) {
      const int m = tid;
      const float s = red[0][m][0] + red[1][m][0] + red[2][m][0] + red[3][m][0];
      const size_t pidx = (size_t)b * NP + m0 + m;
      const float msk = mask[pidx];
      out0[pidx * 2 + 0] = p_in[pidx * 2 + 0] * 4.0f;
      out0[pidx * 2 + 1] = p_in[pidx * 2 + 1] * 4.0f;
      out0[(size_t)2 * NB * NP + pidx] = (s + b3[0]) * msk;
    }
  }
}

extern "C" void kernel_launch(void* const* d_in, const int* in_sizes, int n_in,
                              void* d_out, int out_size, void* d_ws,
                              size_t ws_size, hipStream_t stream) {
  const float* image = (const float*)d_in[0];
  const float* pred  = (const float*)d_in[1];
  const float* mask  = (const float*)d_in[2];
  const float* bw    = (const float*)d_in[3];
  const float* bb    = (const float*)d_in[4];
  const float* oW1   = (const float*)d_in[5];
  const float* ob1   = (const float*)d_in[6];
  const float* oW2   = (const float*)d_in[7];
  const float* ob2   = (const float*)d_in[8];
  const float* oW3   = (const float*)d_in[9];
  const float* ob3   = (const float*)d_in[10];
  const float* cW1   = (const float*)d_in[11];
  const float* cb1   = (const float*)d_in[12];
  const float* cW2   = (const float*)d_in[13];
  const float* cb2   = (const float*)d_in[14];
  const float* cW3   = (const float*)d_in[15];
  const float* cb3   = (const float*)d_in[16];
  float* out = (float*)d_out;

  char* ws = (char*)d_ws;
  unsigned char* feat = (unsigned char*)ws;                // fp8, 25.2 MB
  const size_t featB = (size_t)NB * FH * FW * NC;
  __hip_bfloat16* Xg = (__hip_bfloat16*)(ws + featB);      // 30.4 MB
  float* pyA  = (float*)(Xg + (size_t)NB * NP * P1);
  float* pyB  = pyA + (size_t)NB * NP * 2;
  float* mins = pyB + (size_t)NB * NP * 2;
  __hip_bfloat16* w1b = (__hip_bfloat16*)(mins + 16);     // 4 x [256][P1]
  __hip_bfloat16* w2b = w1b + (size_t)4 * 256 * P1;       // 4 x [256][P2]
  __hip_bfloat16* wcb = w2b + (size_t)4 * 256 * P2;       // [192][64]

  prep_all_kernel<<<dim3(1056, 3), 256, 0, stream>>>(oW1, cW1, oW2, cW2, bw,
                                                     w1b, w2b, wcb);
  conv_kernel<<<dim3(NB * 16384 / 64), 256, 0, stream>>>(image, wcb, bb, feat);

  const float* cur = pred;
  float* nxt = pyA;
  for (int i = 0; i < 3; ++i) {
    mins_kernel<<<dim3(NB), 256, 0, stream>>>(cur, mask, mins);
    gather_kernel<false><<<dim3(NB * NP / 64), 256, 0, stream>>>(
        feat, cur, mask, mins, Xg);
    mlp_kernel<false><<<dim3(NB * NP / 64), 256, 0, stream>>>(
        Xg, cur, mask,
        w1b + (size_t)i * 256 * P1, ob1 + (size_t)i * NSTATE,
        w2b + (size_t)i * 256 * P2, ob2 + (size_t)i * NSTATE,
        oW3 + (size_t)i * 2 * NSTATE, ob3 + (size_t)i * 2, nxt);
    cur = nxt;
    nxt = (nxt == pyA) ? pyB : pyA;
  }
  gather_kernel<true><<<dim3(NB * NP / 64), 256, 0, stream>>>(
      feat, cur, mask, nullptr, Xg);
  mlp_kernel<true><<<dim3(NB * NP / 64), 256, 0, stream>>>(
      Xg, cur, mask, w1b + (size_t)3 * 256 * P1, cb1,
      w2b + (size_t)3 * 256 * P2, cb2, cW3, cb3, out);
}

// Round 10
// 219.155 us; speedup vs baseline: 1.3599x; 1.3599x over previous
//
#include <hip/hip_runtime.h>
#include <hip/hip_bf16.h>
#include <hip/hip_fp8.h>

#define NB 8
#define NP 8192
#define IMH 512
#define IMW 512
#define NC 192
#define FH 128
#define FW 128
#define NSTATE 256

#define P1 232   // bf16 K-pitch for X / W1b (K padded to 224); 116 dw, bank-balanced
#define P2 264   // bf16 K-pitch for H1 / W2b (K=256); 132 dw, bank-balanced
#define K1PAD 224
#define CPITCH 72  // conv im2col LDS pitch (bf16): 144 B -> conflict-free b128

typedef __attribute__((ext_vector_type(8))) unsigned short ush8;
typedef __attribute__((ext_vector_type(8))) short short8v;
typedef __attribute__((ext_vector_type(4))) float f32x4;

__device__ __forceinline__ float bf2f(unsigned short u) {
  return __uint_as_float(((unsigned)u) << 16);
}
__device__ __forceinline__ float fp8tof(unsigned char b) {
  __hip_fp8_e4m3 v;
  v.__x = b;
  return (float)v;
}
__device__ __forceinline__ unsigned char ftofp8(float f) {
  __hip_fp8_e4m3 v(f);
  return v.__x;
}

// ---------------- conv as MFMA GEMM: M=pix, N=192, K=48 -> feat fp8 ----
__global__ __launch_bounds__(256) void conv_kernel(
    const float* __restrict__ img, const __hip_bfloat16* __restrict__ wcb,
    const float* __restrict__ bb, unsigned char* __restrict__ feat) {
  __shared__ __hip_bfloat16 Xim[64 * CPITCH];  // 9 KB

  const int tid = threadIdx.x;
  const int lane = tid & 63;
  const int w = tid >> 6;
  const int cl = lane & 15;
  const int kg = lane >> 4;
  const int b = blockIdx.x & 7;
  const int pix0 = (blockIdx.x >> 3) * 64;
  const int y = pix0 >> 7;
  const int xh = (pix0 >> 6) & 1;

  {
    const int pix = tid & 63;
    const int q = tid >> 6;
    *(uint2*)&Xim[pix * CPITCH + 48 + q * 4] = (uint2){0u, 0u};
  }

#pragma unroll
  for (int it = 0; it < 3; ++it) {
    const int idx = it * 256 + tid;  // 0..767
    const int row = idx >> 6;        // ci*4+ky
    const int c = idx & 63;          // local pixel
    const int ci = row >> 2, ky = row & 3;
    const float4 v = *(const float4*)(img + (((size_t)b * 3 + ci) * IMH +
                                             (y * 4 + ky)) * IMW + xh * 256 + c * 4);
    __hip_bfloat16 h[4];
    h[0] = __float2bfloat16(v.x);
    h[1] = __float2bfloat16(v.y);
    h[2] = __float2bfloat16(v.z);
    h[3] = __float2bfloat16(v.w);
    *(uint2*)&Xim[c * CPITCH + ci * 16 + ky * 4] = *(const uint2*)h;
  }
  __syncthreads();

  f32x4 acc[4][3];
#pragma unroll
  for (int mt = 0; mt < 4; ++mt)
#pragma unroll
    for (int nt = 0; nt < 3; ++nt) acc[mt][nt] = (f32x4){0, 0, 0, 0};

#pragma unroll
  for (int kc = 0; kc < 2; ++kc) {
    short8v af[4], bfv[3];
#pragma unroll
    for (int mt = 0; mt < 4; ++mt)
      af[mt] = *(const short8v*)&Xim[(mt * 16 + cl) * CPITCH + kc * 32 + kg * 8];
#pragma unroll
    for (int nt = 0; nt < 3; ++nt)
      bfv[nt] = *(const short8v*)&wcb[(size_t)(w * 48 + nt * 16 + cl) * 64 +
                                      kc * 32 + kg * 8];
#pragma unroll
    for (int mt = 0; mt < 4; ++mt)
#pragma unroll
      for (int nt = 0; nt < 3; ++nt)
        acc[mt][nt] = __builtin_amdgcn_mfma_f32_16x16x32_bf16(
            af[mt], bfv[nt], acc[mt][nt], 0, 0, 0);
  }

#pragma unroll
  for (int nt = 0; nt < 3; ++nt) {
    const float bias = bb[w * 48 + nt * 16 + cl];
#pragma unroll
    for (int mt = 0; mt < 4; ++mt) {
#pragma unroll
      for (int r = 0; r < 4; ++r) {
        feat[((size_t)(w * 8 + b) * 16384 + pix0 + mt * 16 + kg * 4 + r) * 48 +
             nt * 16 + cl] = ftofp8(acc[mt][nt][r] + bias);
      }
    }
  }
}

// ---------------- fused weight prep ----------------
__global__ void prep_all_kernel(
    const float* __restrict__ oW1, const float* __restrict__ cW1,
    const float* __restrict__ oW2, const float* __restrict__ cW2,
    const float* __restrict__ bw, __hip_bfloat16* __restrict__ w1b,
    __hip_bfloat16* __restrict__ w2b, __hip_bfloat16* __restrict__ wcb) {
  const int idx = blockIdx.x * 256 + threadIdx.x;
  const int region = blockIdx.y;
  if (region == 0) {
    if (idx >= 4 * 256 * P1) return;
    const int L = idx / (256 * P1);
    const int rem = idx - L * (256 * P1);
    const int n = rem / P1;
    const int k = rem - n * P1;
    const float* src = (L < 3) ? (oW1 + (size_t)L * 256 * 194) : cW1;
    const int K = (L < 3) ? 194 : 195;
    w1b[idx] = __float2bfloat16((k < K) ? src[(size_t)n * K + k] : 0.0f);
  } else if (region == 1) {
    if (idx >= 4 * 256 * P2) return;
    const int L = idx / (256 * P2);
    const int rem = idx - L * (256 * P2);
    const int n = rem / P2;
    const int k = rem - n * P2;
    const float* src = (L < 3) ? (oW2 + (size_t)L * 65536) : cW2;
    w2b[idx] = __float2bfloat16((k < 256) ? src[(size_t)n * 256 + k] : 0.0f);
  } else {
    if (idx >= 192 * 64) return;
    const int n = idx >> 6;
    const int k = idx & 63;
    wcb[idx] = __float2bfloat16((k < 48) ? bw[(size_t)n * 48 + k] : 0.0f);
  }
}

// ---------------- per-batch masked min of points ----------------
__global__ void mins_kernel(const float* __restrict__ py,
                            const float* __restrict__ mask,
                            float* __restrict__ mins) {
  int b = blockIdx.x;
  float mx = 1e9f, my = 1e9f;
  for (int n = threadIdx.x; n < NP; n += 256) {
    float m = mask[(size_t)b * NP + n];
    float2 p = *(const float2*)&py[((size_t)b * NP + n) * 2];
    mx = fminf(mx, m > 0.0f ? p.x : 1e9f);
    my = fminf(my, m > 0.0f ? p.y : 1e9f);
  }
#pragma unroll
  for (int o = 32; o > 0; o >>= 1) {
    mx = fminf(mx, __shfl_down(mx, o));
    my = fminf(my, __shfl_down(my, o));
  }
  __shared__ float sx[4], sy[4];
  if ((threadIdx.x & 63) == 0) { sx[threadIdx.x >> 6] = mx; sy[threadIdx.x >> 6] = my; }
  __syncthreads();
  if (threadIdx.x == 0) {
    mx = fminf(fminf(sx[0], sx[1]), fminf(sx[2], sx[3]));
    my = fminf(fminf(sy[0], sy[1]), fminf(sy[2], sy[3]));
    mins[b * 2 + 0] = mx;
    mins[b * 2 + 1] = my;
  }
}

// ---------------- fused gather (fp8 feat) + MFMA MLP, W in registers ----
// block: 64 points x N=256; 4 waves. W1 frags preloaded at entry (overlap
// gather's L2 latency); W2 frags preloaded under GEMM1->GEMM2 transition.
// launch_bounds(256,2): 256-reg budget so the preloads don't spill.
template <bool CLS>
__global__ __launch_bounds__(256, 2) void mlp_kernel(
    const unsigned char* __restrict__ feat,
    const float* __restrict__ p_in,
    const float* __restrict__ mask,
    const float* __restrict__ mins,
    const __hip_bfloat16* __restrict__ W1b, const float* __restrict__ b1,
    const __hip_bfloat16* __restrict__ W2b, const float* __restrict__ b2,
    const float* __restrict__ W3, const float* __restrict__ b3,
    float* __restrict__ out0) {
  __shared__ __hip_bfloat16 Xls[64 * P2];  // X[64][P1] then H1[64][P2]
  __shared__ float red[4][64][2];

  const int tid = threadIdx.x;
  const int lane = tid & 63;
  const int w = tid >> 6;
  const int cl = lane & 15;
  const int kg = lane >> 4;
  const int b = blockIdx.x & 7;             // XCD-aligned batch
  const int m0 = (blockIdx.x >> 3) * 64;

  // ---- preload W1 fragments + epilogue scalars (independent of gather) ----
  short8v w1f[7][4];
#pragma unroll
  for (int kc = 0; kc < 7; ++kc)
#pragma unroll
    for (int nt = 0; nt < 4; ++nt)
      w1f[kc][nt] = *(const short8v*)&W1b[(size_t)(w * 64 + nt * 16 + cl) * P1 +
                                          kc * 32 + kg * 8];
  float b1v[4], b2v[4], w3av[4], w3bv[4];
#pragma unroll
  for (int nt = 0; nt < 4; ++nt) {
    const int n = w * 64 + nt * 16 + cl;
    b1v[nt] = b1[n];
    b2v[nt] = b2[n];
    w3av[nt] = W3[n];
    w3bv[nt] = CLS ? 0.0f : W3[256 + n];
  }

  // ---- gather: thread = (point m = tid>>2, 48-ch slab j = tid&3) ----
  {
    const int m = tid >> 2;
    const int j = tid & 3;
    const int n = m0 + m;
    const size_t pidx = (size_t)b * NP + n;
    const float msk = mask[pidx];
    const float2 pv = *(const float2*)&p_in[pidx * 2];
    const float px = pv.x, pyv = pv.y;
    const float xs = px * (127.0f / 128.0f);
    const float ys = pyv * (127.0f / 128.0f);
    const float x0f = floorf(xs), y0f = floorf(ys);
    const float fx = xs - x0f, fy = ys - y0f;
    const int x0 = (int)fminf(fmaxf(x0f, 0.0f), 127.0f);
    const int x1 = (int)fminf(fmaxf(x0f + 1.0f, 0.0f), 127.0f);
    const int y0 = (int)fminf(fmaxf(y0f, 0.0f), 127.0f);
    const int y1 = (int)fminf(fmaxf(y0f + 1.0f, 0.0f), 127.0f);
    const float w00 = (1.0f - fy) * (1.0f - fx);
    const float w01 = (1.0f - fy) * fx;
    const float w10 = fy * (1.0f - fx);
    const float w11 = fy * fx;
    const unsigned char* fb = feat + (size_t)(j * 8 + b) * 16384 * 48;
    const uint4* r00 = (const uint4*)(fb + (size_t)(y0 * FW + x0) * 48);
    const uint4* r01 = (const uint4*)(fb + (size_t)(y0 * FW + x1) * 48);
    const uint4* r10 = (const uint4*)(fb + (size_t)(y1 * FW + x0) * 48);
    const uint4* r11 = (const uint4*)(fb + (size_t)(y1 * FW + x1) * 48);
#pragma unroll
    for (int v = 0; v < 3; ++v) {
      union { uint4 u; unsigned char c[16]; } a0, a1, a2, a3;
      a0.u = r00[v]; a1.u = r01[v]; a2.u = r10[v]; a3.u = r11[v];
      __hip_bfloat16 h[16];
#pragma unroll
      for (int e = 0; e < 16; ++e) {
        float gg = w00 * fp8tof(a0.c[e]) + w01 * fp8tof(a1.c[e]) +
                   w10 * fp8tof(a2.c[e]) + w11 * fp8tof(a3.c[e]);
        h[e] = __float2bfloat16(gg * msk);
      }
      *(ush8*)&Xls[m * P1 + j * 48 + v * 16 + 0] = *(const ush8*)&h[0];
      *(ush8*)&Xls[m * P1 + j * 48 + v * 16 + 8] = *(const ush8*)&h[8];
    }
    if (j == 0) {
      __hip_bfloat16 ex[32];
#pragma unroll
      for (int i = 0; i < 32; ++i) ex[i] = __float2bfloat16(0.0f);
      if constexpr (!CLS) {
        ex[0] = __float2bfloat16((px - mins[b * 2 + 0]) * msk);
        ex[1] = __float2bfloat16((pyv - mins[b * 2 + 1]) * msk);
      } else {
        ex[0] = __float2bfloat16(px);
        ex[1] = __float2bfloat16(pyv);
        const int npv = (n + NP - 1) & (NP - 1);
        const int nnx = (n + 1) & (NP - 1);
        const float2 pp = *(const float2*)&p_in[((size_t)b * NP + npv) * 2];
        const float2 pn = *(const float2*)&p_in[((size_t)b * NP + nnx) * 2];
        const float v1x = pp.x - px, v1y = pp.y - pyv;
        const float v2x = pn.x - px, v2y = pn.y - pyv;
        const float dot = v1x * v2x + v1y * v2y;
        const float nrm =
            sqrtf(v1x * v1x + v1y * v1y) * sqrtf(v2x * v2x + v2y * v2y);
        const float ca = fminf(fmaxf(dot / (nrm + 1e-8f), -1.0f), 1.0f);
        ex[2] = __float2bfloat16(acosf(ca) * msk);
      }
#pragma unroll
      for (int q = 0; q < 4; ++q)
        *(ush8*)&Xls[m * P1 + 192 + q * 8] = *(const ush8*)&ex[q * 8];
    }
  }
  __syncthreads();

  // ---- GEMM1: H1 = relu(X @ W1^T + b1); W already in registers ----
  f32x4 acc[4][4];
#pragma unroll
  for (int mt = 0; mt < 4; ++mt)
#pragma unroll
    for (int nt = 0; nt < 4; ++nt) acc[mt][nt] = (f32x4){0, 0, 0, 0};

#pragma unroll
  for (int kc = 0; kc < 7; ++kc) {
    short8v af[4];
#pragma unroll
    for (int mt = 0; mt < 4; ++mt)
      af[mt] = *(const short8v*)&Xls[(mt * 16 + cl) * P1 + kc * 32 + kg * 8];
#pragma unroll
    for (int mt = 0; mt < 4; ++mt)
#pragma unroll
      for (int nt = 0; nt < 4; ++nt)
        acc[mt][nt] = __builtin_amdgcn_mfma_f32_16x16x32_bf16(
            af[mt], w1f[kc][nt], acc[mt][nt], 0, 0, 0);
  }

  // ---- preload W2 fragments (complete under H1 writeback + barrier) ----
  short8v w2f[8][4];
#pragma unroll
  for (int kc = 0; kc < 8; ++kc)
#pragma unroll
    for (int nt = 0; nt < 4; ++nt)
      w2f[kc][nt] = *(const short8v*)&W2b[(size_t)(w * 64 + nt * 16 + cl) * P2 +
                                          kc * 32 + kg * 8];
  __syncthreads();  // Xls X-view no longer needed

  // H1 (bias+relu, bf16) -> Xls as [m][P2]
#pragma unroll
  for (int nt = 0; nt < 4; ++nt) {
    const float bias = b1v[nt];
    const int n = w * 64 + nt * 16 + cl;
#pragma unroll
    for (int mt = 0; mt < 4; ++mt) {
#pragma unroll
      for (int r = 0; r < 4; ++r) {
        const float v = fmaxf(acc[mt][nt][r] + bias, 0.0f);
        Xls[(mt * 16 + kg * 4 + r) * P2 + n] = __float2bfloat16(v);
      }
    }
  }
  __syncthreads();

  // ---- GEMM2: W in registers ----
  f32x4 acc2[4][4];
#pragma unroll
  for (int mt = 0; mt < 4; ++mt)
#pragma unroll
    for (int nt = 0; nt < 4; ++nt) acc2[mt][nt] = (f32x4){0, 0, 0, 0};

#pragma unroll
  for (int kc = 0; kc < 8; ++kc) {
    short8v af[4];
#pragma unroll
    for (int mt = 0; mt < 4; ++mt)
      af[mt] = *(const short8v*)&Xls[(mt * 16 + cl) * P2 + kc * 32 + kg * 8];
#pragma unroll
    for (int mt = 0; mt < 4; ++mt)
#pragma unroll
      for (int nt = 0; nt < 4; ++nt)
        acc2[mt][nt] = __builtin_amdgcn_mfma_f32_16x16x32_bf16(
            af[mt], w2f[kc][nt], acc2[mt][nt], 0, 0, 0);
  }

  // ---- GEMM3 (f32) + reduction + epilogue ----
  float pr[4][4][2];
#pragma unroll
  for (int mt = 0; mt < 4; ++mt)
#pragma unroll
    for (int r = 0; r < 4; ++r) { pr[mt][r][0] = 0.0f; pr[mt][r][1] = 0.0f; }

#pragma unroll
  for (int nt = 0; nt < 4; ++nt) {
    const float bias = b2v[nt];
    const float w3a = w3av[nt];
    const float w3b = w3bv[nt];
#pragma unroll
    for (int mt = 0; mt < 4; ++mt) {
#pragma unroll
      for (int r = 0; r < 4; ++r) {
        const float t = fmaxf(acc2[mt][nt][r] + bias, 0.0f);
        pr[mt][r][0] = fmaf(t, w3a, pr[mt][r][0]);
        if constexpr (!CLS) pr[mt][r][1] = fmaf(t, w3b, pr[mt][r][1]);
      }
    }
  }
#pragma unroll
  for (int s = 1; s < 16; s <<= 1) {
#pragma unroll
    for (int mt = 0; mt < 4; ++mt)
#pragma unroll
      for (int r = 0; r < 4; ++r) {
        pr[mt][r][0] += __shfl_xor(pr[mt][r][0], s);
        if constexpr (!CLS) pr[mt][r][1] += __shfl_xor(pr[mt][r][1], s);
      }
  }
  if constexpr (!CLS) {
    if (cl < 8) {
      const int r = cl >> 1, o = cl & 1;
#pragma unroll
      for (int mt = 0; mt < 4; ++mt)
        red[w][mt * 16 + kg * 4 + r][o] = pr[mt][r][o];
    }
  } else {
    if (cl < 4) {
      const int r = cl;
#pragma unroll
      for (int mt = 0; mt < 4; ++mt)
        red[w][mt * 16 + kg * 4 + r][0] = pr[mt][r][0];
    }
  }
  __syncthreads();

  if constexpr (!CLS) {
    if (tid < 128) {
      const int m = tid >> 1, o = tid & 1;
      const float s = red[0][m][o] + red[1][m][o] + red[2][m][o] + red[3][m][o];
      const size_t pidx = (size_t)b * NP + m0 + m;
      const float msk = mask[pidx];
      const float off = (s + b3[o]) * msk;
      out0[pidx * 2 + o] = p_in[pidx * 2 + o] + off * 4.0f;
    }
  } else {
    if (tid < 64) {
      const int m = tid;
      const float s = red[0][m][0] + red[1][m][0] + red[2][m][0] + red[3][m][0];
      const size_t pidx = (size_t)b * NP + m0 + m;
      const float msk = mask[pidx];
      out0[pidx * 2 + 0] = p_in[pidx * 2 + 0] * 4.0f;
      out0[pidx * 2 + 1] = p_in[pidx * 2 + 1] * 4.0f;
      out0[(size_t)2 * NB * NP + pidx] = (s + b3[0]) * msk;
    }
  }
}

extern "C" void kernel_launch(void* const* d_in, const int* in_sizes, int n_in,
                              void* d_out, int out_size, void* d_ws,
                              size_t ws_size, hipStream_t stream) {
  const float* image = (const float*)d_in[0];
  const float* pred  = (const float*)d_in[1];
  const float* mask  = (const float*)d_in[2];
  const float* bw    = (const float*)d_in[3];
  const float* bb    = (const float*)d_in[4];
  const float* oW1   = (const float*)d_in[5];
  const float* ob1   = (const float*)d_in[6];
  const float* oW2   = (const float*)d_in[7];
  const float* ob2   = (const float*)d_in[8];
  const float* oW3   = (const float*)d_in[9];
  const float* ob3   = (const float*)d_in[10];
  const float* cW1   = (const float*)d_in[11];
  const float* cb1   = (const float*)d_in[12];
  const float* cW2   = (const float*)d_in[13];
  const float* cb2   = (const float*)d_in[14];
  const float* cW3   = (const float*)d_in[15];
  const float* cb3   = (const float*)d_in[16];
  float* out = (float*)d_out;

  char* ws = (char*)d_ws;
  unsigned char* feat = (unsigned char*)ws;                // fp8, 25.2 MB
  const size_t featB = (size_t)NB * FH * FW * NC;
  float* pyA  = (float*)(ws + featB);
  float* pyB  = pyA + (size_t)NB * NP * 2;
  float* mins = pyB + (size_t)NB * NP * 2;
  __hip_bfloat16* w1b = (__hip_bfloat16*)(mins + 16);     // 4 x [256][P1]
  __hip_bfloat16* w2b = w1b + (size_t)4 * 256 * P1;       // 4 x [256][P2]
  __hip_bfloat16* wcb = w2b + (size_t)4 * 256 * P2;       // [192][64]

  prep_all_kernel<<<dim3(1056, 3), 256, 0, stream>>>(oW1, cW1, oW2, cW2, bw,
                                                     w1b, w2b, wcb);
  conv_kernel<<<dim3(NB * 16384 / 64), 256, 0, stream>>>(image, wcb, bb, feat);

  const float* cur = pred;
  float* nxt = pyA;
  for (int i = 0; i < 3; ++i) {
    mins_kernel<<<dim3(NB), 256, 0, stream>>>(cur, mask, mins);
    mlp_kernel<false><<<dim3(NB * NP / 64), 256, 0, stream>>>(
        feat, cur, mask, mins,
        w1b + (size_t)i * 256 * P1, ob1 + (size_t)i * NSTATE,
        w2b + (size_t)i * 256 * P2, ob2 + (size_t)i * NSTATE,
        oW3 + (size_t)i * 2 * NSTATE, ob3 + (size_t)i * 2, nxt);
    cur = nxt;
    nxt = (nxt == pyA) ? pyB : pyA;
  }
  mlp_kernel<true><<<dim3(NB * NP / 64), 256, 0, stream>>>(
      feat, cur, mask, nullptr, w1b + (size_t)3 * 256 * P1, cb1,
      w2b + (size_t)3 * 256 * P2, cb2, cW3, cb3, out);
}

// Round 11
// 208.418 us; speedup vs baseline: 1.4299x; 1.0515x over previous
//
#include <hip/hip_runtime.h>
#include <hip/hip_bf16.h>
#include <hip/hip_fp8.h>

#define NB 8
#define NP 8192
#define IMH 512
#define IMW 512
#define NC 192
#define FH 128
#define FW 128
#define NSTATE 256

#define P1 232   // bf16 K-pitch for X / W1b (K padded to 224); 116 dw, bank-balanced
#define P2 264   // bf16 K-pitch for H1 / W2b (K=256); 132 dw, bank-balanced
#define K1PAD 224
#define CPITCH 72  // conv im2col LDS pitch (bf16): 144 B -> conflict-free b128

typedef __attribute__((ext_vector_type(8))) unsigned short ush8;
typedef __attribute__((ext_vector_type(8))) short short8v;
typedef __attribute__((ext_vector_type(4))) float f32x4;

__device__ __forceinline__ float bf2f(unsigned short u) {
  return __uint_as_float(((unsigned)u) << 16);
}
__device__ __forceinline__ float fp8tof(unsigned char b) {
  __hip_fp8_e4m3 v;
  v.__x = b;
  return (float)v;
}
__device__ __forceinline__ unsigned char ftofp8(float f) {
  __hip_fp8_e4m3 v(f);
  return v.__x;
}
// monotone float<->uint encoding: min on floats == min on encoded uints
__device__ __forceinline__ unsigned fenc(float f) {
  unsigned u = __float_as_uint(f);
  return (u & 0x80000000u) ? ~u : (u | 0x80000000u);
}
__device__ __forceinline__ float fdec(unsigned u) {
  return __uint_as_float((u & 0x80000000u) ? (u & 0x7FFFFFFFu) : ~u);
}

// ---------------- conv as MFMA GEMM: M=pix, N=192, K=48 -> feat fp8 ----
__global__ __launch_bounds__(256) void conv_kernel(
    const float* __restrict__ img, const __hip_bfloat16* __restrict__ wcb,
    const float* __restrict__ bb, unsigned char* __restrict__ feat) {
  __shared__ __hip_bfloat16 Xim[64 * CPITCH];  // 9 KB

  const int tid = threadIdx.x;
  const int lane = tid & 63;
  const int w = tid >> 6;
  const int cl = lane & 15;
  const int kg = lane >> 4;
  const int b = blockIdx.x & 7;
  const int pix0 = (blockIdx.x >> 3) * 64;
  const int y = pix0 >> 7;
  const int xh = (pix0 >> 6) & 1;

  {
    const int pix = tid & 63;
    const int q = tid >> 6;
    *(uint2*)&Xim[pix * CPITCH + 48 + q * 4] = (uint2){0u, 0u};
  }

#pragma unroll
  for (int it = 0; it < 3; ++it) {
    const int idx = it * 256 + tid;  // 0..767
    const int row = idx >> 6;        // ci*4+ky
    const int c = idx & 63;          // local pixel
    const int ci = row >> 2, ky = row & 3;
    const float4 v = *(const float4*)(img + (((size_t)b * 3 + ci) * IMH +
                                             (y * 4 + ky)) * IMW + xh * 256 + c * 4);
    __hip_bfloat16 h[4];
    h[0] = __float2bfloat16(v.x);
    h[1] = __float2bfloat16(v.y);
    h[2] = __float2bfloat16(v.z);
    h[3] = __float2bfloat16(v.w);
    *(uint2*)&Xim[c * CPITCH + ci * 16 + ky * 4] = *(const uint2*)h;
  }
  __syncthreads();

  f32x4 acc[4][3];
#pragma unroll
  for (int mt = 0; mt < 4; ++mt)
#pragma unroll
    for (int nt = 0; nt < 3; ++nt) acc[mt][nt] = (f32x4){0, 0, 0, 0};

#pragma unroll
  for (int kc = 0; kc < 2; ++kc) {
    short8v af[4], bfv[3];
#pragma unroll
    for (int mt = 0; mt < 4; ++mt)
      af[mt] = *(const short8v*)&Xim[(mt * 16 + cl) * CPITCH + kc * 32 + kg * 8];
#pragma unroll
    for (int nt = 0; nt < 3; ++nt)
      bfv[nt] = *(const short8v*)&wcb[(size_t)(w * 48 + nt * 16 + cl) * 64 +
                                      kc * 32 + kg * 8];
#pragma unroll
    for (int mt = 0; mt < 4; ++mt)
#pragma unroll
      for (int nt = 0; nt < 3; ++nt)
        acc[mt][nt] = __builtin_amdgcn_mfma_f32_16x16x32_bf16(
            af[mt], bfv[nt], acc[mt][nt], 0, 0, 0);
  }

#pragma unroll
  for (int nt = 0; nt < 3; ++nt) {
    const float bias = bb[w * 48 + nt * 16 + cl];
#pragma unroll
    for (int mt = 0; mt < 4; ++mt) {
#pragma unroll
      for (int r = 0; r < 4; ++r) {
        feat[((size_t)(w * 8 + b) * 16384 + pix0 + mt * 16 + kg * 4 + r) * 48 +
             nt * 16 + cl] = ftofp8(acc[mt][nt][r] + bias);
      }
    }
  }
}

// ---------------- fused weight prep + mins init + pass-0 mins ----------------
// region 0: W1 -> bf16 [256][P1]; region 1: W2 -> bf16 [256][P2];
// region 2: conv W -> bf16 [192][64] + init mins slots 1..3 to enc(1e9);
// region 3: masked min of pred_points -> mins slot 0 (encoded).
__global__ void prep_all_kernel(
    const float* __restrict__ oW1, const float* __restrict__ cW1,
    const float* __restrict__ oW2, const float* __restrict__ cW2,
    const float* __restrict__ bw, const float* __restrict__ pred,
    const float* __restrict__ mask, __hip_bfloat16* __restrict__ w1b,
    __hip_bfloat16* __restrict__ w2b, __hip_bfloat16* __restrict__ wcb,
    unsigned* __restrict__ mins4) {
  __shared__ float sx[4], sy[4];
  const int idx = blockIdx.x * 256 + threadIdx.x;
  const int region = blockIdx.y;
  if (region == 0) {
    if (idx >= 4 * 256 * P1) return;
    const int L = idx / (256 * P1);
    const int rem = idx - L * (256 * P1);
    const int n = rem / P1;
    const int k = rem - n * P1;
    const float* src = (L < 3) ? (oW1 + (size_t)L * 256 * 194) : cW1;
    const int K = (L < 3) ? 194 : 195;
    w1b[idx] = __float2bfloat16((k < K) ? src[(size_t)n * K + k] : 0.0f);
  } else if (region == 1) {
    if (idx >= 4 * 256 * P2) return;
    const int L = idx / (256 * P2);
    const int rem = idx - L * (256 * P2);
    const int n = rem / P2;
    const int k = rem - n * P2;
    const float* src = (L < 3) ? (oW2 + (size_t)L * 65536) : cW2;
    w2b[idx] = __float2bfloat16((k < 256) ? src[(size_t)n * 256 + k] : 0.0f);
  } else if (region == 2) {
    if (idx < 48) mins4[16 + idx] = fenc(1e9f);  // slots 1..3
    if (idx >= 192 * 64) return;
    const int n = idx >> 6;
    const int k = idx & 63;
    wcb[idx] = __float2bfloat16((k < 48) ? bw[(size_t)n * 48 + k] : 0.0f);
  } else {
    if (blockIdx.x >= 8) return;
    const int b = blockIdx.x;
    float mx = 1e9f, my = 1e9f;
    for (int n = threadIdx.x; n < NP; n += 256) {
      float m = mask[(size_t)b * NP + n];
      float2 p = *(const float2*)&pred[((size_t)b * NP + n) * 2];
      mx = fminf(mx, m > 0.0f ? p.x : 1e9f);
      my = fminf(my, m > 0.0f ? p.y : 1e9f);
    }
#pragma unroll
    for (int o = 32; o > 0; o >>= 1) {
      mx = fminf(mx, __shfl_down(mx, o));
      my = fminf(my, __shfl_down(my, o));
    }
    if ((threadIdx.x & 63) == 0) {
      sx[threadIdx.x >> 6] = mx;
      sy[threadIdx.x >> 6] = my;
    }
    __syncthreads();
    if (threadIdx.x == 0) {
      mx = fminf(fminf(sx[0], sx[1]), fminf(sx[2], sx[3]));
      my = fminf(fminf(sy[0], sy[1]), fminf(sy[2], sy[3]));
      mins4[b * 2 + 0] = fenc(mx);
      mins4[b * 2 + 1] = fenc(my);
    }
  }
}

// ---------------- fused gather (fp8 feat) + MFMA MLP ----------------
// W1 frags preloaded at entry (dead after GEMM1); W2 1-deep pipelined so
// nothing big lives across the barriers -> no scratch spill.
template <bool CLS>
__global__ __launch_bounds__(256, 2) void mlp_kernel(
    const unsigned char* __restrict__ feat,
    const float* __restrict__ p_in,
    const float* __restrict__ mask,
    const unsigned* __restrict__ mins_in,
    unsigned* __restrict__ mins_out,
    const __hip_bfloat16* __restrict__ W1b, const float* __restrict__ b1,
    const __hip_bfloat16* __restrict__ W2b, const float* __restrict__ b2,
    const float* __restrict__ W3, const float* __restrict__ b3,
    float* __restrict__ out0) {
  __shared__ __hip_bfloat16 Xls[64 * P2];  // X[64][P1] then H1[64][P2]
  __shared__ float red[4][64][2];

  const int tid = threadIdx.x;
  const int lane = tid & 63;
  const int w = tid >> 6;
  const int cl = lane & 15;
  const int kg = lane >> 4;
  const int b = blockIdx.x & 7;             // XCD-aligned batch
  const int m0 = (blockIdx.x >> 3) * 64;

  // ---- preload W1 fragments + epilogue scalars (overlap gather latency) ----
  short8v w1f[7][4];
#pragma unroll
  for (int kc = 0; kc < 7; ++kc)
#pragma unroll
    for (int nt = 0; nt < 4; ++nt)
      w1f[kc][nt] = *(const short8v*)&W1b[(size_t)(w * 64 + nt * 16 + cl) * P1 +
                                          kc * 32 + kg * 8];
  float b1v[4], b2v[4], w3av[4], w3bv[4];
#pragma unroll
  for (int nt = 0; nt < 4; ++nt) {
    const int n = w * 64 + nt * 16 + cl;
    b1v[nt] = b1[n];
    b2v[nt] = b2[n];
    w3av[nt] = W3[n];
    w3bv[nt] = CLS ? 0.0f : W3[256 + n];
  }

  // ---- gather: thread = (point m = tid>>2, 48-ch slab j = tid&3) ----
  {
    const int m = tid >> 2;
    const int j = tid & 3;
    const int n = m0 + m;
    const size_t pidx = (size_t)b * NP + n;
    const float msk = mask[pidx];
    const float2 pv = *(const float2*)&p_in[pidx * 2];
    const float px = pv.x, pyv = pv.y;
    const float xs = px * (127.0f / 128.0f);
    const float ys = pyv * (127.0f / 128.0f);
    const float x0f = floorf(xs), y0f = floorf(ys);
    const float fx = xs - x0f, fy = ys - y0f;
    const int x0 = (int)fminf(fmaxf(x0f, 0.0f), 127.0f);
    const int x1 = (int)fminf(fmaxf(x0f + 1.0f, 0.0f), 127.0f);
    const int y0 = (int)fminf(fmaxf(y0f, 0.0f), 127.0f);
    const int y1 = (int)fminf(fmaxf(y0f + 1.0f, 0.0f), 127.0f);
    const float w00 = (1.0f - fy) * (1.0f - fx);
    const float w01 = (1.0f - fy) * fx;
    const float w10 = fy * (1.0f - fx);
    const float w11 = fy * fx;
    const unsigned char* fb = feat + (size_t)(j * 8 + b) * 16384 * 48;
    const uint4* r00 = (const uint4*)(fb + (size_t)(y0 * FW + x0) * 48);
    const uint4* r01 = (const uint4*)(fb + (size_t)(y0 * FW + x1) * 48);
    const uint4* r10 = (const uint4*)(fb + (size_t)(y1 * FW + x0) * 48);
    const uint4* r11 = (const uint4*)(fb + (size_t)(y1 * FW + x1) * 48);
#pragma unroll
    for (int v = 0; v < 3; ++v) {
      union { uint4 u; unsigned char c[16]; } a0, a1, a2, a3;
      a0.u = r00[v]; a1.u = r01[v]; a2.u = r10[v]; a3.u = r11[v];
      __hip_bfloat16 h[16];
#pragma unroll
      for (int e = 0; e < 16; ++e) {
        float gg = w00 * fp8tof(a0.c[e]) + w01 * fp8tof(a1.c[e]) +
                   w10 * fp8tof(a2.c[e]) + w11 * fp8tof(a3.c[e]);
        h[e] = __float2bfloat16(gg * msk);
      }
      *(ush8*)&Xls[m * P1 + j * 48 + v * 16 + 0] = *(const ush8*)&h[0];
      *(ush8*)&Xls[m * P1 + j * 48 + v * 16 + 8] = *(const ush8*)&h[8];
    }
    if (j == 0) {
      __hip_bfloat16 ex[32];
#pragma unroll
      for (int i = 0; i < 32; ++i) ex[i] = __float2bfloat16(0.0f);
      if constexpr (!CLS) {
        ex[0] = __float2bfloat16((px - fdec(mins_in[b * 2 + 0])) * msk);
        ex[1] = __float2bfloat16((pyv - fdec(mins_in[b * 2 + 1])) * msk);
      } else {
        ex[0] = __float2bfloat16(px);
        ex[1] = __float2bfloat16(pyv);
        const int npv = (n + NP - 1) & (NP - 1);
        const int nnx = (n + 1) & (NP - 1);
        const float2 pp = *(const float2*)&p_in[((size_t)b * NP + npv) * 2];
        const float2 pn = *(const float2*)&p_in[((size_t)b * NP + nnx) * 2];
        const float v1x = pp.x - px, v1y = pp.y - pyv;
        const float v2x = pn.x - px, v2y = pn.y - pyv;
        const float dot = v1x * v2x + v1y * v2y;
        const float nrm =
            sqrtf(v1x * v1x + v1y * v1y) * sqrtf(v2x * v2x + v2y * v2y);
        const float ca = fminf(fmaxf(dot / (nrm + 1e-8f), -1.0f), 1.0f);
        ex[2] = __float2bfloat16(acosf(ca) * msk);
      }
#pragma unroll
      for (int q = 0; q < 4; ++q)
        *(ush8*)&Xls[m * P1 + 192 + q * 8] = *(const ush8*)&ex[q * 8];
    }
  }
  __syncthreads();

  // ---- GEMM1: H1 = relu(X @ W1^T + b1); W1 in registers ----
  f32x4 acc[4][4];
#pragma unroll
  for (int mt = 0; mt < 4; ++mt)
#pragma unroll
    for (int nt = 0; nt < 4; ++nt) acc[mt][nt] = (f32x4){0, 0, 0, 0};

#pragma unroll
  for (int kc = 0; kc < 7; ++kc) {
    short8v af[4];
#pragma unroll
    for (int mt = 0; mt < 4; ++mt)
      af[mt] = *(const short8v*)&Xls[(mt * 16 + cl) * P1 + kc * 32 + kg * 8];
#pragma unroll
    for (int mt = 0; mt < 4; ++mt)
#pragma unroll
      for (int nt = 0; nt < 4; ++nt)
        acc[mt][nt] = __builtin_amdgcn_mfma_f32_16x16x32_bf16(
            af[mt], w1f[kc][nt], acc[mt][nt], 0, 0, 0);
  }

  // issue W2 chunk-0 loads (only 16 regs live across barrier)
  short8v w2c[4];
#pragma unroll
  for (int nt = 0; nt < 4; ++nt)
    w2c[nt] = *(const short8v*)&W2b[(size_t)(w * 64 + nt * 16 + cl) * P2 +
                                    kg * 8];
  __syncthreads();  // Xls X-view no longer needed

  // H1 (bias+relu, bf16) -> Xls as [m][P2]
#pragma unroll
  for (int nt = 0; nt < 4; ++nt) {
    const float bias = b1v[nt];
    const int n = w * 64 + nt * 16 + cl;
#pragma unroll
    for (int mt = 0; mt < 4; ++mt) {
#pragma unroll
      for (int r = 0; r < 4; ++r) {
        const float v = fmaxf(acc[mt][nt][r] + bias, 0.0f);
        Xls[(mt * 16 + kg * 4 + r) * P2 + n] = __float2bfloat16(v);
      }
    }
  }
  __syncthreads();

  // ---- GEMM2: W2 1-deep prefetch pipeline ----
  f32x4 acc2[4][4];
#pragma unroll
  for (int mt = 0; mt < 4; ++mt)
#pragma unroll
    for (int nt = 0; nt < 4; ++nt) acc2[mt][nt] = (f32x4){0, 0, 0, 0};

#pragma unroll
  for (int kc = 0; kc < 8; ++kc) {
    short8v w2n[4];
    if (kc < 7) {
#pragma unroll
      for (int nt = 0; nt < 4; ++nt)
        w2n[nt] = *(const short8v*)&W2b[(size_t)(w * 64 + nt * 16 + cl) * P2 +
                                        (kc + 1) * 32 + kg * 8];
    }
    short8v af[4];
#pragma unroll
    for (int mt = 0; mt < 4; ++mt)
      af[mt] = *(const short8v*)&Xls[(mt * 16 + cl) * P2 + kc * 32 + kg * 8];
#pragma unroll
    for (int mt = 0; mt < 4; ++mt)
#pragma unroll
      for (int nt = 0; nt < 4; ++nt)
        acc2[mt][nt] = __builtin_amdgcn_mfma_f32_16x16x32_bf16(
            af[mt], w2c[nt], acc2[mt][nt], 0, 0, 0);
    if (kc < 7) {
#pragma unroll
      for (int nt = 0; nt < 4; ++nt) w2c[nt] = w2n[nt];
    }
  }

  // ---- GEMM3 (f32) + reduction + epilogue ----
  float pr[4][4][2];
#pragma unroll
  for (int mt = 0; mt < 4; ++mt)
#pragma unroll
    for (int r = 0; r < 4; ++r) { pr[mt][r][0] = 0.0f; pr[mt][r][1] = 0.0f; }

#pragma unroll
  for (int nt = 0; nt < 4; ++nt) {
    const float bias = b2v[nt];
    const float w3a = w3av[nt];
    const float w3b = w3bv[nt];
#pragma unroll
    for (int mt = 0; mt < 4; ++mt) {
#pragma unroll
      for (int r = 0; r < 4; ++r) {
        const float t = fmaxf(acc2[mt][nt][r] + bias, 0.0f);
        pr[mt][r][0] = fmaf(t, w3a, pr[mt][r][0]);
        if constexpr (!CLS) pr[mt][r][1] = fmaf(t, w3b, pr[mt][r][1]);
      }
    }
  }
#pragma unroll
  for (int s = 1; s < 16; s <<= 1) {
#pragma unroll
    for (int mt = 0; mt < 4; ++mt)
#pragma unroll
      for (int r = 0; r < 4; ++r) {
        pr[mt][r][0] += __shfl_xor(pr[mt][r][0], s);
        if constexpr (!CLS) pr[mt][r][1] += __shfl_xor(pr[mt][r][1], s);
      }
  }
  if constexpr (!CLS) {
    if (cl < 8) {
      const int r = cl >> 1, o = cl & 1;
#pragma unroll
      for (int mt = 0; mt < 4; ++mt)
        red[w][mt * 16 + kg * 4 + r][o] = pr[mt][r][o];
    }
  } else {
    if (cl < 4) {
      const int r = cl;
#pragma unroll
      for (int mt = 0; mt < 4; ++mt)
        red[w][mt * 16 + kg * 4 + r][0] = pr[mt][r][0];
    }
  }
  __syncthreads();

  if constexpr (!CLS) {
    if (tid < 128) {
      const int m = tid >> 1, o = tid & 1;
      const float s = red[0][m][o] + red[1][m][o] + red[2][m][o] + red[3][m][o];
      const size_t pidx = (size_t)b * NP + m0 + m;
      const float msk = mask[pidx];
      const float off = (s + b3[o]) * msk;
      const float nv = p_in[pidx * 2 + o] + off * 4.0f;
      out0[pidx * 2 + o] = nv;
      // fused masked-min for the NEXT pass's canonical coords
      float mval = (msk > 0.0f) ? nv : 1e9f;
#pragma unroll
      for (int st = 2; st < 64; st <<= 1)
        mval = fminf(mval, __shfl_xor(mval, st));
      if ((tid & 63) < 2 && mins_out != nullptr)
        atomicMin(&mins_out[b * 2 + o], fenc(mval));
    }
  } else {
    if (tid < 64) {
      const int m = tid;
      const float s = red[0][m][0] + red[1][m][0] + red[2][m][0] + red[3][m][0];
      const size_t pidx = (size_t)b * NP + m0 + m;
      const float msk = mask[pidx];
      out0[pidx * 2 + 0] = p_in[pidx * 2 + 0] * 4.0f;
      out0[pidx * 2 + 1] = p_in[pidx * 2 + 1] * 4.0f;
      out0[(size_t)2 * NB * NP + pidx] = (s + b3[0]) * msk;
    }
  }
}

extern "C" void kernel_launch(void* const* d_in, const int* in_sizes, int n_in,
                              void* d_out, int out_size, void* d_ws,
                              size_t ws_size, hipStream_t stream) {
  const float* image = (const float*)d_in[0];
  const float* pred  = (const float*)d_in[1];
  const float* mask  = (const float*)d_in[2];
  const float* bw    = (const float*)d_in[3];
  const float* bb    = (const float*)d_in[4];
  const float* oW1   = (const float*)d_in[5];
  const float* ob1   = (const float*)d_in[6];
  const float* oW2   = (const float*)d_in[7];
  const float* ob2   = (const float*)d_in[8];
  const float* oW3   = (const float*)d_in[9];
  const float* ob3   = (const float*)d_in[10];
  const float* cW1   = (const float*)d_in[11];
  const float* cb1   = (const float*)d_in[12];
  const float* cW2   = (const float*)d_in[13];
  const float* cb2   = (const float*)d_in[14];
  const float* cW3   = (const float*)d_in[15];
  const float* cb3   = (const float*)d_in[16];
  float* out = (float*)d_out;

  char* ws = (char*)d_ws;
  unsigned char* feat = (unsigned char*)ws;                // fp8, 25.2 MB
  const size_t featB = (size_t)NB * FH * FW * NC;
  float* pyA  = (float*)(ws + featB);
  float* pyB  = pyA + (size_t)NB * NP * 2;
  unsigned* mins4 = (unsigned*)(pyB + (size_t)NB * NP * 2);  // [4][16] encoded
  __hip_bfloat16* w1b = (__hip_bfloat16*)(mins4 + 64);    // 4 x [256][P1]
  __hip_bfloat16* w2b = w1b + (size_t)4 * 256 * P1;       // 4 x [256][P2]
  __hip_bfloat16* wcb = w2b + (size_t)4 * 256 * P2;       // [192][64]

  prep_all_kernel<<<dim3(1056, 4), 256, 0, stream>>>(
      oW1, cW1, oW2, cW2, bw, pred, mask, w1b, w2b, wcb, mins4);
  conv_kernel<<<dim3(NB * 16384 / 64), 256, 0, stream>>>(image, wcb, bb, feat);

  const float* cur = pred;
  float* nxt = pyA;
  for (int i = 0; i < 3; ++i) {
    mlp_kernel<false><<<dim3(NB * NP / 64), 256, 0, stream>>>(
        feat, cur, mask, mins4 + i * 16,
        (i < 2) ? (mins4 + (i + 1) * 16) : nullptr,
        w1b + (size_t)i * 256 * P1, ob1 + (size_t)i * NSTATE,
        w2b + (size_t)i * 256 * P2, ob2 + (size_t)i * NSTATE,
        oW3 + (size_t)i * 2 * NSTATE, ob3 + (size_t)i * 2, nxt);
    cur = nxt;
    nxt = (nxt == pyA) ? pyB : pyA;
  }
  mlp_kernel<true><<<dim3(NB * NP / 64), 256, 0, stream>>>(
      feat, cur, mask, nullptr, nullptr, w1b + (size_t)3 * 256 * P1, cb1,
      w2b + (size_t)3 * 256 * P2, cb2, cW3, cb3, out);
}

// Round 12
// 208.212 us; speedup vs baseline: 1.4313x; 1.0010x over previous
//
#include <hip/hip_runtime.h>
#include <hip/hip_bf16.h>
#include <hip/hip_fp8.h>

#define NB 8
#define NP 8192
#define IMH 512
#define IMW 512
#define NC 192
#define FH 128
#define FW 128
#define NSTATE 256

#define P1 232   // bf16 K-pitch for X / W1b (K padded to 224); 116 dw, bank-balanced
#define P2 264   // bf16 K-pitch for H1 / W2b (K=256); 132 dw, bank-balanced
#define K1PAD 224
#define CPITCH 72  // conv im2col LDS pitch (bf16): 144 B -> conflict-free b128

typedef __attribute__((ext_vector_type(8))) unsigned short ush8;
typedef __attribute__((ext_vector_type(8))) short short8v;
typedef __attribute__((ext_vector_type(4))) float f32x4;

__device__ __forceinline__ float bf2f(unsigned short u) {
  return __uint_as_float(((unsigned)u) << 16);
}
__device__ __forceinline__ float fp8tof(unsigned char b) {
  __hip_fp8_e4m3 v;
  v.__x = b;
  return (float)v;
}
__device__ __forceinline__ unsigned char ftofp8(float f) {
  __hip_fp8_e4m3 v(f);
  return v.__x;
}
// monotone float<->uint encoding: min on floats == min on encoded uints
__device__ __forceinline__ unsigned fenc(float f) {
  unsigned u = __float_as_uint(f);
  return (u & 0x80000000u) ? ~u : (u | 0x80000000u);
}
__device__ __forceinline__ float fdec(unsigned u) {
  return __uint_as_float((u & 0x80000000u) ? (u & 0x7FFFFFFFu) : ~u);
}

// ---------------- conv as MFMA GEMM: M=pix, N=192, K=48 -> feat fp8 ----
__global__ __launch_bounds__(256) void conv_kernel(
    const float* __restrict__ img, const __hip_bfloat16* __restrict__ wcb,
    const float* __restrict__ bb, unsigned char* __restrict__ feat) {
  __shared__ __hip_bfloat16 Xim[64 * CPITCH];  // 9 KB

  const int tid = threadIdx.x;
  const int lane = tid & 63;
  const int w = tid >> 6;
  const int cl = lane & 15;
  const int kg = lane >> 4;
  const int b = blockIdx.x & 7;
  const int pix0 = (blockIdx.x >> 3) * 64;
  const int y = pix0 >> 7;
  const int xh = (pix0 >> 6) & 1;

  {
    const int pix = tid & 63;
    const int q = tid >> 6;
    *(uint2*)&Xim[pix * CPITCH + 48 + q * 4] = (uint2){0u, 0u};
  }

#pragma unroll
  for (int it = 0; it < 3; ++it) {
    const int idx = it * 256 + tid;  // 0..767
    const int row = idx >> 6;        // ci*4+ky
    const int c = idx & 63;          // local pixel
    const int ci = row >> 2, ky = row & 3;
    const float4 v = *(const float4*)(img + (((size_t)b * 3 + ci) * IMH +
                                             (y * 4 + ky)) * IMW + xh * 256 + c * 4);
    __hip_bfloat16 h[4];
    h[0] = __float2bfloat16(v.x);
    h[1] = __float2bfloat16(v.y);
    h[2] = __float2bfloat16(v.z);
    h[3] = __float2bfloat16(v.w);
    *(uint2*)&Xim[c * CPITCH + ci * 16 + ky * 4] = *(const uint2*)h;
  }
  __syncthreads();

  f32x4 acc[4][3];
#pragma unroll
  for (int mt = 0; mt < 4; ++mt)
#pragma unroll
    for (int nt = 0; nt < 3; ++nt) acc[mt][nt] = (f32x4){0, 0, 0, 0};

#pragma unroll
  for (int kc = 0; kc < 2; ++kc) {
    short8v af[4], bfv[3];
#pragma unroll
    for (int mt = 0; mt < 4; ++mt)
      af[mt] = *(const short8v*)&Xim[(mt * 16 + cl) * CPITCH + kc * 32 + kg * 8];
#pragma unroll
    for (int nt = 0; nt < 3; ++nt)
      bfv[nt] = *(const short8v*)&wcb[(size_t)(w * 48 + nt * 16 + cl) * 64 +
                                      kc * 32 + kg * 8];
#pragma unroll
    for (int mt = 0; mt < 4; ++mt)
#pragma unroll
      for (int nt = 0; nt < 3; ++nt)
        acc[mt][nt] = __builtin_amdgcn_mfma_f32_16x16x32_bf16(
            af[mt], bfv[nt], acc[mt][nt], 0, 0, 0);
  }

#pragma unroll
  for (int nt = 0; nt < 3; ++nt) {
    const float bias = bb[w * 48 + nt * 16 + cl];
#pragma unroll
    for (int mt = 0; mt < 4; ++mt) {
#pragma unroll
      for (int r = 0; r < 4; ++r) {
        feat[((size_t)(w * 8 + b) * 16384 + pix0 + mt * 16 + kg * 4 + r) * 48 +
             nt * 16 + cl] = ftofp8(acc[mt][nt][r] + bias);
      }
    }
  }
}

// ---------------- fused weight prep + mins init + pass-0 mins ----------------
__global__ void prep_all_kernel(
    const float* __restrict__ oW1, const float* __restrict__ cW1,
    const float* __restrict__ oW2, const float* __restrict__ cW2,
    const float* __restrict__ bw, const float* __restrict__ pred,
    const float* __restrict__ mask, __hip_bfloat16* __restrict__ w1b,
    __hip_bfloat16* __restrict__ w2b, __hip_bfloat16* __restrict__ wcb,
    unsigned* __restrict__ mins4) {
  __shared__ float sx[4], sy[4];
  const int idx = blockIdx.x * 256 + threadIdx.x;
  const int region = blockIdx.y;
  if (region == 0) {
    if (idx >= 4 * 256 * P1) return;
    const int L = idx / (256 * P1);
    const int rem = idx - L * (256 * P1);
    const int n = rem / P1;
    const int k = rem - n * P1;
    const float* src = (L < 3) ? (oW1 + (size_t)L * 256 * 194) : cW1;
    const int K = (L < 3) ? 194 : 195;
    w1b[idx] = __float2bfloat16((k < K) ? src[(size_t)n * K + k] : 0.0f);
  } else if (region == 1) {
    if (idx >= 4 * 256 * P2) return;
    const int L = idx / (256 * P2);
    const int rem = idx - L * (256 * P2);
    const int n = rem / P2;
    const int k = rem - n * P2;
    const float* src = (L < 3) ? (oW2 + (size_t)L * 65536) : cW2;
    w2b[idx] = __float2bfloat16((k < 256) ? src[(size_t)n * 256 + k] : 0.0f);
  } else if (region == 2) {
    if (idx < 48) mins4[16 + idx] = fenc(1e9f);  // slots 1..3
    if (idx >= 192 * 64) return;
    const int n = idx >> 6;
    const int k = idx & 63;
    wcb[idx] = __float2bfloat16((k < 48) ? bw[(size_t)n * 48 + k] : 0.0f);
  } else {
    if (blockIdx.x >= 8) return;
    const int b = blockIdx.x;
    float mx = 1e9f, my = 1e9f;
    for (int n = threadIdx.x; n < NP; n += 256) {
      float m = mask[(size_t)b * NP + n];
      float2 p = *(const float2*)&pred[((size_t)b * NP + n) * 2];
      mx = fminf(mx, m > 0.0f ? p.x : 1e9f);
      my = fminf(my, m > 0.0f ? p.y : 1e9f);
    }
#pragma unroll
    for (int o = 32; o > 0; o >>= 1) {
      mx = fminf(mx, __shfl_down(mx, o));
      my = fminf(my, __shfl_down(my, o));
    }
    if ((threadIdx.x & 63) == 0) {
      sx[threadIdx.x >> 6] = mx;
      sy[threadIdx.x >> 6] = my;
    }
    __syncthreads();
    if (threadIdx.x == 0) {
      mx = fminf(fminf(sx[0], sx[1]), fminf(sx[2], sx[3]));
      my = fminf(fminf(sy[0], sy[1]), fminf(sy[2], sy[3]));
      mins4[b * 2 + 0] = fenc(mx);
      mins4[b * 2 + 1] = fenc(my);
    }
  }
}

// ---------------- fused gather (fp8 feat) + MFMA MLP ----------------
// Preload placement tuned for register liveness (round-11 lesson):
//  - gather runs FIRST with no big preloads live (~80 regs peak);
//  - W1 frags loaded AFTER gather, latency hidden by the barrier wait;
//  - W2 frags loaded after GEMM1, hidden under barrier + H1 writeback.
// Peak liveness ~210 < 256 budget of launch_bounds(256,2) -> no scratch.
template <bool CLS>
__global__ __launch_bounds__(256, 2) void mlp_kernel(
    const unsigned char* __restrict__ feat,
    const float* __restrict__ p_in,
    const float* __restrict__ mask,
    const unsigned* __restrict__ mins_in,
    unsigned* __restrict__ mins_out,
    const __hip_bfloat16* __restrict__ W1b, const float* __restrict__ b1,
    const __hip_bfloat16* __restrict__ W2b, const float* __restrict__ b2,
    const float* __restrict__ W3, const float* __restrict__ b3,
    float* __restrict__ out0) {
  __shared__ __hip_bfloat16 Xls[64 * P2];  // X[64][P1] then H1[64][P2]
  __shared__ float red[4][64][2];

  const int tid = threadIdx.x;
  const int lane = tid & 63;
  const int w = tid >> 6;
  const int cl = lane & 15;
  const int kg = lane >> 4;
  const int b = blockIdx.x & 7;             // XCD-aligned batch
  const int m0 = (blockIdx.x >> 3) * 64;

  // ---- gather: thread = (point m = tid>>2, 48-ch slab j = tid&3) ----
  {
    const int m = tid >> 2;
    const int j = tid & 3;
    const int n = m0 + m;
    const size_t pidx = (size_t)b * NP + n;
    const float msk = mask[pidx];
    const float2 pv = *(const float2*)&p_in[pidx * 2];
    const float px = pv.x, pyv = pv.y;
    const float xs = px * (127.0f / 128.0f);
    const float ys = pyv * (127.0f / 128.0f);
    const float x0f = floorf(xs), y0f = floorf(ys);
    const float fx = xs - x0f, fy = ys - y0f;
    const int x0 = (int)fminf(fmaxf(x0f, 0.0f), 127.0f);
    const int x1 = (int)fminf(fmaxf(x0f + 1.0f, 0.0f), 127.0f);
    const int y0 = (int)fminf(fmaxf(y0f, 0.0f), 127.0f);
    const int y1 = (int)fminf(fmaxf(y0f + 1.0f, 0.0f), 127.0f);
    const float w00 = (1.0f - fy) * (1.0f - fx);
    const float w01 = (1.0f - fy) * fx;
    const float w10 = fy * (1.0f - fx);
    const float w11 = fy * fx;
    const unsigned char* fb = feat + (size_t)(j * 8 + b) * 16384 * 48;
    const uint4* r00 = (const uint4*)(fb + (size_t)(y0 * FW + x0) * 48);
    const uint4* r01 = (const uint4*)(fb + (size_t)(y0 * FW + x1) * 48);
    const uint4* r10 = (const uint4*)(fb + (size_t)(y1 * FW + x0) * 48);
    const uint4* r11 = (const uint4*)(fb + (size_t)(y1 * FW + x1) * 48);
#pragma unroll
    for (int v = 0; v < 3; ++v) {
      union { uint4 u; unsigned char c[16]; } a0, a1, a2, a3;
      a0.u = r00[v]; a1.u = r01[v]; a2.u = r10[v]; a3.u = r11[v];
      __hip_bfloat16 h[16];
#pragma unroll
      for (int e = 0; e < 16; ++e) {
        float gg = w00 * fp8tof(a0.c[e]) + w01 * fp8tof(a1.c[e]) +
                   w10 * fp8tof(a2.c[e]) + w11 * fp8tof(a3.c[e]);
        h[e] = __float2bfloat16(gg * msk);
      }
      *(ush8*)&Xls[m * P1 + j * 48 + v * 16 + 0] = *(const ush8*)&h[0];
      *(ush8*)&Xls[m * P1 + j * 48 + v * 16 + 8] = *(const ush8*)&h[8];
    }
    if (j == 0) {
      __hip_bfloat16 ex[32];
#pragma unroll
      for (int i = 0; i < 32; ++i) ex[i] = __float2bfloat16(0.0f);
      if constexpr (!CLS) {
        ex[0] = __float2bfloat16((px - fdec(mins_in[b * 2 + 0])) * msk);
        ex[1] = __float2bfloat16((pyv - fdec(mins_in[b * 2 + 1])) * msk);
      } else {
        ex[0] = __float2bfloat16(px);
        ex[1] = __float2bfloat16(pyv);
        const int npv = (n + NP - 1) & (NP - 1);
        const int nnx = (n + 1) & (NP - 1);
        const float2 pp = *(const float2*)&p_in[((size_t)b * NP + npv) * 2];
        const float2 pn = *(const float2*)&p_in[((size_t)b * NP + nnx) * 2];
        const float v1x = pp.x - px, v1y = pp.y - pyv;
        const float v2x = pn.x - px, v2y = pn.y - pyv;
        const float dot = v1x * v2x + v1y * v2y;
        const float nrm =
            sqrtf(v1x * v1x + v1y * v1y) * sqrtf(v2x * v2x + v2y * v2y);
        const float ca = fminf(fmaxf(dot / (nrm + 1e-8f), -1.0f), 1.0f);
        ex[2] = __float2bfloat16(acosf(ca) * msk);
      }
#pragma unroll
      for (int q = 0; q < 4; ++q)
        *(ush8*)&Xls[m * P1 + 192 + q * 8] = *(const ush8*)&ex[q * 8];
    }
  }

  // ---- NOW preload W1 fragments + epilogue scalars: latency hides under
  // the barrier wait for other waves' gathers; live range starts here ----
  short8v w1f[7][4];
#pragma unroll
  for (int kc = 0; kc < 7; ++kc)
#pragma unroll
    for (int nt = 0; nt < 4; ++nt)
      w1f[kc][nt] = *(const short8v*)&W1b[(size_t)(w * 64 + nt * 16 + cl) * P1 +
                                          kc * 32 + kg * 8];
  float b1v[4], b2v[4], w3av[4], w3bv[4];
#pragma unroll
  for (int nt = 0; nt < 4; ++nt) {
    const int n = w * 64 + nt * 16 + cl;
    b1v[nt] = b1[n];
    b2v[nt] = b2[n];
    w3av[nt] = W3[n];
    w3bv[nt] = CLS ? 0.0f : W3[256 + n];
  }
  __syncthreads();

  // ---- GEMM1: H1 = relu(X @ W1^T + b1); W1 in registers ----
  f32x4 acc[4][4];
#pragma unroll
  for (int mt = 0; mt < 4; ++mt)
#pragma unroll
    for (int nt = 0; nt < 4; ++nt) acc[mt][nt] = (f32x4){0, 0, 0, 0};

#pragma unroll
  for (int kc = 0; kc < 7; ++kc) {
    short8v af[4];
#pragma unroll
    for (int mt = 0; mt < 4; ++mt)
      af[mt] = *(const short8v*)&Xls[(mt * 16 + cl) * P1 + kc * 32 + kg * 8];
#pragma unroll
    for (int mt = 0; mt < 4; ++mt)
#pragma unroll
      for (int nt = 0; nt < 4; ++nt)
        acc[mt][nt] = __builtin_amdgcn_mfma_f32_16x16x32_bf16(
            af[mt], w1f[kc][nt], acc[mt][nt], 0, 0, 0);
  }

  // ---- preload W2 fragments; w1f now dead, so liveness stays bounded;
  // loads complete under barrier + H1 writeback + barrier ----
  short8v w2f[8][4];
#pragma unroll
  for (int kc = 0; kc < 8; ++kc)
#pragma unroll
    for (int nt = 0; nt < 4; ++nt)
      w2f[kc][nt] = *(const short8v*)&W2b[(size_t)(w * 64 + nt * 16 + cl) * P2 +
                                          kc * 32 + kg * 8];
  __syncthreads();  // Xls X-view no longer needed

  // H1 (bias+relu, bf16) -> Xls as [m][P2]
#pragma unroll
  for (int nt = 0; nt < 4; ++nt) {
    const float bias = b1v[nt];
    const int n = w * 64 + nt * 16 + cl;
#pragma unroll
    for (int mt = 0; mt < 4; ++mt) {
#pragma unroll
      for (int r = 0; r < 4; ++r) {
        const float v = fmaxf(acc[mt][nt][r] + bias, 0.0f);
        Xls[(mt * 16 + kg * 4 + r) * P2 + n] = __float2bfloat16(v);
      }
    }
  }
  __syncthreads();

  // ---- GEMM2: W2 in registers ----
  f32x4 acc2[4][4];
#pragma unroll
  for (int mt = 0; mt < 4; ++mt)
#pragma unroll
    for (int nt = 0; nt < 4; ++nt) acc2[mt][nt] = (f32x4){0, 0, 0, 0};

#pragma unroll
  for (int kc = 0; kc < 8; ++kc) {
    short8v af[4];
#pragma unroll
    for (int mt = 0; mt < 4; ++mt)
      af[mt] = *(const short8v*)&Xls[(mt * 16 + cl) * P2 + kc * 32 + kg * 8];
#pragma unroll
    for (int mt = 0; mt < 4; ++mt)
#pragma unroll
      for (int nt = 0; nt < 4; ++nt)
        acc2[mt][nt] = __builtin_amdgcn_mfma_f32_16x16x32_bf16(
            af[mt], w2f[kc][nt], acc2[mt][nt], 0, 0, 0);
  }

  // ---- GEMM3 (f32) + reduction + epilogue ----
  float pr[4][4][2];
#pragma unroll
  for (int mt = 0; mt < 4; ++mt)
#pragma unroll
    for (int r = 0; r < 4; ++r) { pr[mt][r][0] = 0.0f; pr[mt][r][1] = 0.0f; }

#pragma unroll
  for (int nt = 0; nt < 4; ++nt) {
    const float bias = b2v[nt];
    const float w3a = w3av[nt];
    const float w3b = w3bv[nt];
#pragma unroll
    for (int mt = 0; mt < 4; ++mt) {
#pragma unroll
      for (int r = 0; r < 4; ++r) {
        const float t = fmaxf(acc2[mt][nt][r] + bias, 0.0f);
        pr[mt][r][0] = fmaf(t, w3a, pr[mt][r][0]);
        if constexpr (!CLS) pr[mt][r][1] = fmaf(t, w3b, pr[mt][r][1]);
      }
    }
  }
#pragma unroll
  for (int s = 1; s < 16; s <<= 1) {
#pragma unroll
    for (int mt = 0; mt < 4; ++mt)
#pragma unroll
      for (int r = 0; r < 4; ++r) {
        pr[mt][r][0] += __shfl_xor(pr[mt][r][0], s);
        if constexpr (!CLS) pr[mt][r][1] += __shfl_xor(pr[mt][r][1], s);
      }
  }
  if constexpr (!CLS) {
    if (cl < 8) {
      const int r = cl >> 1, o = cl & 1;
#pragma unroll
      for (int mt = 0; mt < 4; ++mt)
        red[w][mt * 16 + kg * 4 + r][o] = pr[mt][r][o];
    }
  } else {
    if (cl < 4) {
      const int r = cl;
#pragma unroll
      for (int mt = 0; mt < 4; ++mt)
        red[w][mt * 16 + kg * 4 + r][0] = pr[mt][r][0];
    }
  }
  __syncthreads();

  if constexpr (!CLS) {
    if (tid < 128) {
      const int m = tid >> 1, o = tid & 1;
      const float s = red[0][m][o] + red[1][m][o] + red[2][m][o] + red[3][m][o];
      const size_t pidx = (size_t)b * NP + m0 + m;
      const float msk = mask[pidx];
      const float off = (s + b3[o]) * msk;
      const float nv = p_in[pidx * 2 + o] + off * 4.0f;
      out0[pidx * 2 + o] = nv;
      // fused masked-min for the NEXT pass's canonical coords
      float mval = (msk > 0.0f) ? nv : 1e9f;
#pragma unroll
      for (int st = 2; st < 64; st <<= 1)
        mval = fminf(mval, __shfl_xor(mval, st));
      if ((tid & 63) < 2 && mins_out != nullptr)
        atomicMin(&mins_out[b * 2 + o], fenc(mval));
    }
  } else {
    if (tid < 64) {
      const int m = tid;
      const float s = red[0][m][0] + red[1][m][0] + red[2][m][0] + red[3][m][0];
      const size_t pidx = (size_t)b * NP + m0 + m;
      const float msk = mask[pidx];
      out0[pidx * 2 + 0] = p_in[pidx * 2 + 0] * 4.0f;
      out0[pidx * 2 + 1] = p_in[pidx * 2 + 1] * 4.0f;
      out0[(size_t)2 * NB * NP + pidx] = (s + b3[0]) * msk;
    }
  }
}

extern "C" void kernel_launch(void* const* d_in, const int* in_sizes, int n_in,
                              void* d_out, int out_size, void* d_ws,
                              size_t ws_size, hipStream_t stream) {
  const float* image = (const float*)d_in[0];
  const float* pred  = (const float*)d_in[1];
  const float* mask  = (const float*)d_in[2];
  const float* bw    = (const float*)d_in[3];
  const float* bb    = (const float*)d_in[4];
  const float* oW1   = (const float*)d_in[5];
  const float* ob1   = (const float*)d_in[6];
  const float* oW2   = (const float*)d_in[7];
  const float* ob2   = (const float*)d_in[8];
  const float* oW3   = (const float*)d_in[9];
  const float* ob3   = (const float*)d_in[10];
  const float* cW1   = (const float*)d_in[11];
  const float* cb1   = (const float*)d_in[12];
  const float* cW2   = (const float*)d_in[13];
  const float* cb2   = (const float*)d_in[14];
  const float* cW3   = (const float*)d_in[15];
  const float* cb3   = (const float*)d_in[16];
  float* out = (float*)d_out;

  char* ws = (char*)d_ws;
  unsigned char* feat = (unsigned char*)ws;                // fp8, 25.2 MB
  const size_t featB = (size_t)NB * FH * FW * NC;
  float* pyA  = (float*)(ws + featB);
  float* pyB  = pyA + (size_t)NB * NP * 2;
  unsigned* mins4 = (unsigned*)(pyB + (size_t)NB * NP * 2);  // [4][16] encoded
  __hip_bfloat16* w1b = (__hip_bfloat16*)(mins4 + 64);    // 4 x [256][P1]
  __hip_bfloat16* w2b = w1b + (size_t)4 * 256 * P1;       // 4 x [256][P2]
  __hip_bfloat16* wcb = w2b + (size_t)4 * 256 * P2;       // [192][64]

  prep_all_kernel<<<dim3(1056, 4), 256, 0, stream>>>(
      oW1, cW1, oW2, cW2, bw, pred, mask, w1b, w2b, wcb, mins4);
  conv_kernel<<<dim3(NB * 16384 / 64), 256, 0, stream>>>(image, wcb, bb, feat);

  const float* cur = pred;
  float* nxt = pyA;
  for (int i = 0; i < 3; ++i) {
    mlp_kernel<false><<<dim3(NB * NP / 64), 256, 0, stream>>>(
        feat, cur, mask, mins4 + i * 16,
        (i < 2) ? (mins4 + (i + 1) * 16) : nullptr,
        w1b + (size_t)i * 256 * P1, ob1 + (size_t)i * NSTATE,
        w2b + (size_t)i * 256 * P2, ob2 + (size_t)i * NSTATE,
        oW3 + (size_t)i * 2 * NSTATE, ob3 + (size_t)i * 2, nxt);
    cur = nxt;
    nxt = (nxt == pyA) ? pyB : pyA;
  }
  mlp_kernel<true><<<dim3(NB * NP / 64), 256, 0, stream>>>(
      feat, cur, mask, nullptr, nullptr, w1b + (size_t)3 * 256 * P1, cb1,
      w2b + (size_t)3 * 256 * P2, cb2, cW3, cb3, out);
}